// Round 2
// baseline (9738.001 us; speedup 1.0000x reference)
//
#include <hip/hip_runtime.h>

#define ND 128
#define ED 32
#define HD 256

__device__ __forceinline__ float silu_f(float v) {
  return v / (1.0f + __expf(-v));
}

// Register-blocked GEMM tile: 64 rows x 256 cols, K streamed.
// Thread (ty=t>>4, tx=t&15) computes rows {2ty,2ty+1} x 16 cols
// (j = g*64 + tx*4 + jj).  A in LDS (stride AS), W streamed from global (L1/L2-hot).
template<int AS>
__device__ __forceinline__ void gemm_tile(const float (*A)[AS], int eA, int kBeg, int kEnd,
                                          int wBeg, const float* __restrict__ W, int tx,
                                          float acc[2][16])
{
  #pragma unroll 4
  for (int k = kBeg; k < kEnd; ++k) {
    float a0 = A[eA][k];
    float a1 = A[eA + 1][k];
    const float* wr = W + (size_t)(wBeg + (k - kBeg)) * HD + tx * 4;
    #pragma unroll
    for (int g = 0; g < 4; ++g) {
      float4 w = *reinterpret_cast<const float4*>(wr + g * 64);
      acc[0][g*4+0] += a0 * w.x; acc[0][g*4+1] += a0 * w.y;
      acc[0][g*4+2] += a0 * w.z; acc[0][g*4+3] += a0 * w.w;
      acc[1][g*4+0] += a1 * w.x; acc[1][g*4+1] += a1 * w.y;
      acc[1][g*4+2] += a1 * w.z; acc[1][g*4+3] += a1 * w.w;
    }
  }
}

__device__ __forceinline__ void load_bias(const float* __restrict__ b, int tx,
                                          float acc[2][16])
{
  #pragma unroll
  for (int g = 0; g < 4; ++g) {
    float4 bv = *reinterpret_cast<const float4*>(b + g*64 + tx*4);
    acc[0][g*4+0]=bv.x; acc[0][g*4+1]=bv.y; acc[0][g*4+2]=bv.z; acc[0][g*4+3]=bv.w;
    acc[1][g*4+0]=bv.x; acc[1][g*4+1]=bv.y; acc[1][g*4+2]=bv.z; acc[1][g*4+3]=bv.w;
  }
}

// ---------------------------------------------------------------------------
// Edge kernel: per 64-edge tile, builds edge_in in LDS, runs the 3 edge GEMMs,
// scatters m_i (segment_sum of msg) and x_agg (segment_sum of dx*coef).
// ONE overlaid LDS buffer (edge_in -> m1 -> m): 64x292 = 74.75KB -> 2 blocks/CU.
// ---------------------------------------------------------------------------
__global__ __launch_bounds__(512, 4)
void egnn_edge_kernel(const float* __restrict__ h, const float* __restrict__ x,
                      const int* __restrict__ eidx, const float* __restrict__ eattr,
                      const float* __restrict__ mW1, const float* __restrict__ mb1,
                      const float* __restrict__ mW2, const float* __restrict__ mb2,
                      const float* __restrict__ cW1, const float* __restrict__ cb1,
                      const float* __restrict__ cW2,
                      float* __restrict__ m_i, float* __restrict__ x_agg,
                      int N, int E)
{
  // Phase A (edge_in): [0..127]=h[row], [128..255]=h[col], [256]=dist_sq,
  // [260..291]=edge_attr (attr shifted +3 keeps float4 stores 16B-aligned;
  // weight row for attr col k is 257+(k-260)).
  // Phase B: cols 0..255 = m1 = silu(edge_in@mW1+mb1)
  // Phase C: cols 0..255 = m  = silu(m1@mW2+mb2)
  __shared__ float sBuf[64][292];
  __shared__ int   sRow[64];
  __shared__ float sDx[64][3];
  __shared__ float sCw2[HD];

  const int t  = threadIdx.x;
  const int e0 = blockIdx.x * 64;

  { // ---- stage: 8 threads per edge ----
    const int e = t >> 3, part = t & 7;
    const int ge = e0 + e;
    if (ge < E) {
      const int r = eidx[ge], c = eidx[E + ge];
      const float* hsrc = (part < 4) ? (h + (size_t)r * ND + (part & 3) * 32)
                                     : (h + (size_t)c * ND + (part & 3) * 32);
      float* dst = &sBuf[e][(part < 4 ? 0 : 128) + (part & 3) * 32];
      #pragma unroll
      for (int i = 0; i < 8; ++i)
        reinterpret_cast<float4*>(dst)[i] = reinterpret_cast<const float4*>(hsrc)[i];
      reinterpret_cast<float4*>(&sBuf[e][260])[part] =
          reinterpret_cast<const float4*>(eattr + (size_t)ge * ED)[part];
      if (part == 0) {
        sRow[e] = r;
        float dx0 = x[3*(size_t)r+0] - x[3*(size_t)c+0];
        float dx1 = x[3*(size_t)r+1] - x[3*(size_t)c+1];
        float dx2 = x[3*(size_t)r+2] - x[3*(size_t)c+2];
        sDx[e][0] = dx0; sDx[e][1] = dx1; sDx[e][2] = dx2;
        sBuf[e][256] = dx0*dx0 + dx1*dx1 + dx2*dx2 + 1e-8f;
      }
    }
    if (t < HD) sCw2[t] = cW2[t];
  }
  __syncthreads();

  const int ty = t >> 4, tx = t & 15;
  const int eA = 2 * ty;
  const bool val0 = (e0 + eA)     < E;
  const bool val1 = (e0 + eA + 1) < E;

  float acc[2][16];

  // ---- GEMM1: m1 = silu(edge_in @ mW1 + mb1) ----
  load_bias(mb1, tx, acc);
  gemm_tile<292>(sBuf, eA, 0, 257, 0, mW1, tx, acc);       // h_row|h_col|dist
  gemm_tile<292>(sBuf, eA, 260, 292, 257, mW1, tx, acc);   // edge_attr
  __syncthreads();                       // all waves done READING edge_in
  #pragma unroll
  for (int q = 0; q < 16; ++q) {
    int j = (q >> 2) * 64 + tx * 4 + (q & 3);
    sBuf[eA][j]     = silu_f(acc[0][q]);
    sBuf[eA + 1][j] = silu_f(acc[1][q]);
  }
  __syncthreads();

  // ---- GEMM2: m = silu(m1 @ mW2 + mb2) ----
  load_bias(mb2, tx, acc);
  gemm_tile<292>(sBuf, eA, 0, 256, 0, mW2, tx, acc);
  #pragma unroll
  for (int q = 0; q < 16; ++q) { acc[0][q] = silu_f(acc[0][q]); acc[1][q] = silu_f(acc[1][q]); }

  const int r0 = sRow[eA], r1 = sRow[eA + 1];
  // segment_sum(m, row) via HW fp32 atomics
  #pragma unroll
  for (int q = 0; q < 16; ++q) {
    int j = (q >> 2) * 64 + tx * 4 + (q & 3);
    if (val0) unsafeAtomicAdd(&m_i[(size_t)r0 * HD + j], acc[0][q]);
    if (val1) unsafeAtomicAdd(&m_i[(size_t)r1 * HD + j], acc[1][q]);
  }
  __syncthreads();                       // all waves done READING m1
  #pragma unroll
  for (int q = 0; q < 16; ++q) {
    int j = (q >> 2) * 64 + tx * 4 + (q & 3);
    sBuf[eA][j]     = acc[0][q];
    sBuf[eA + 1][j] = acc[1][q];
  }
  __syncthreads();

  // ---- GEMM3: c1 = silu(m @ cW1 + cb1); coef = c1 @ cW2 ----
  load_bias(cb1, tx, acc);
  gemm_tile<292>(sBuf, eA, 0, 256, 0, cW1, tx, acc);
  float p0 = 0.f, p1 = 0.f;
  #pragma unroll
  for (int q = 0; q < 16; ++q) {
    int j = (q >> 2) * 64 + tx * 4 + (q & 3);
    float w2 = sCw2[j];
    p0 += silu_f(acc[0][q]) * w2;
    p1 += silu_f(acc[1][q]) * w2;
  }
  #pragma unroll
  for (int off = 1; off < 16; off <<= 1) {
    p0 += __shfl_xor(p0, off, 16);
    p1 += __shfl_xor(p1, off, 16);
  }
  if (tx == 0) {
    if (val0) {
      unsafeAtomicAdd(&x_agg[3*(size_t)r0+0], sDx[eA][0] * p0);
      unsafeAtomicAdd(&x_agg[3*(size_t)r0+1], sDx[eA][1] * p0);
      unsafeAtomicAdd(&x_agg[3*(size_t)r0+2], sDx[eA][2] * p0);
    }
    if (val1) {
      unsafeAtomicAdd(&x_agg[3*(size_t)r1+0], sDx[eA+1][0] * p1);
      unsafeAtomicAdd(&x_agg[3*(size_t)r1+1], sDx[eA+1][1] * p1);
      unsafeAtomicAdd(&x_agg[3*(size_t)r1+2], sDx[eA+1][2] * p1);
    }
  }
}

// ---------------------------------------------------------------------------
// Node kernel 1: t1 = silu([h, m_i] @ nW1 + nb1)   (K=384, out 256)
// ---------------------------------------------------------------------------
__global__ __launch_bounds__(512)
void egnn_node1_kernel(const float* __restrict__ h, const float* __restrict__ m_i,
                       const float* __restrict__ nW1, const float* __restrict__ nb1,
                       float* __restrict__ t1, int N)
{
  __shared__ float sA[64][388];
  const int t = threadIdx.x;
  const int n0 = blockIdx.x * 64;
  { const int e = t >> 3, part = t & 7, n = n0 + e;
    if (n < N) {
      const float4* hs = reinterpret_cast<const float4*>(h + (size_t)n * ND);
      float4* d1 = reinterpret_cast<float4*>(&sA[e][part * 16]);
      #pragma unroll
      for (int i = 0; i < 4; ++i) d1[i] = hs[part * 4 + i];
      const float4* ms = reinterpret_cast<const float4*>(m_i + (size_t)n * HD);
      float4* d2 = reinterpret_cast<float4*>(&sA[e][128 + part * 32]);
      #pragma unroll
      for (int i = 0; i < 8; ++i) d2[i] = ms[part * 8 + i];
    }
  }
  __syncthreads();
  const int ty = t >> 4, tx = t & 15;
  const int eA = 2 * ty;
  float acc[2][16];
  load_bias(nb1, tx, acc);
  gemm_tile<388>(sA, eA, 0, 384, 0, nW1, tx, acc);
  #pragma unroll
  for (int er = 0; er < 2; ++er) {
    const int n = n0 + eA + er;
    if (n < N) {
      #pragma unroll
      for (int g = 0; g < 4; ++g) {
        float4 o;
        o.x = silu_f(acc[er][g*4+0]); o.y = silu_f(acc[er][g*4+1]);
        o.z = silu_f(acc[er][g*4+2]); o.w = silu_f(acc[er][g*4+3]);
        *reinterpret_cast<float4*>(t1 + (size_t)n * HD + g*64 + tx*4) = o;
      }
    }
  }
}

// ---------------------------------------------------------------------------
// Node kernel 2: h_res = h + t1 @ nW2 + nb2; LayerNorm -> h_out  (K=256, out 128)
// ---------------------------------------------------------------------------
__global__ __launch_bounds__(512)
void egnn_node2_kernel(const float* __restrict__ t1, const float* __restrict__ h,
                       const float* __restrict__ nW2, const float* __restrict__ nb2,
                       const float* __restrict__ gamma, const float* __restrict__ beta,
                       float* __restrict__ hout, int N)
{
  __shared__ float sT[64][260];
  const int t = threadIdx.x;
  const int n0 = blockIdx.x * 64;
  { const int e = t >> 3, part = t & 7, n = n0 + e;
    if (n < N) {
      const float4* src = reinterpret_cast<const float4*>(t1 + (size_t)n * HD + part * 32);
      float4* dst = reinterpret_cast<float4*>(&sT[e][part * 32]);
      #pragma unroll
      for (int i = 0; i < 8; ++i) dst[i] = src[i];
    }
  }
  __syncthreads();
  const int ty = t >> 4, tx = t & 15;
  const int eA = 2 * ty;
  float acc[2][8];
  #pragma unroll
  for (int g = 0; g < 2; ++g) {
    float4 b = *reinterpret_cast<const float4*>(nb2 + g*64 + tx*4);
    acc[0][g*4+0]=b.x; acc[0][g*4+1]=b.y; acc[0][g*4+2]=b.z; acc[0][g*4+3]=b.w;
    acc[1][g*4+0]=b.x; acc[1][g*4+1]=b.y; acc[1][g*4+2]=b.z; acc[1][g*4+3]=b.w;
  }
  #pragma unroll 4
  for (int k = 0; k < 256; ++k) {
    float a0 = sT[eA][k], a1 = sT[eA+1][k];
    const float* wr = nW2 + (size_t)k * ND + tx * 4;
    #pragma unroll
    for (int g = 0; g < 2; ++g) {
      float4 w = *reinterpret_cast<const float4*>(wr + g * 64);
      acc[0][g*4+0] += a0*w.x; acc[0][g*4+1] += a0*w.y;
      acc[0][g*4+2] += a0*w.z; acc[0][g*4+3] += a0*w.w;
      acc[1][g*4+0] += a1*w.x; acc[1][g*4+1] += a1*w.y;
      acc[1][g*4+2] += a1*w.z; acc[1][g*4+3] += a1*w.w;
    }
  }
  #pragma unroll
  for (int er = 0; er < 2; ++er) {
    const int n = n0 + eA + er;
    float v[8];
    float s = 0.f, s2 = 0.f;
    #pragma unroll
    for (int g = 0; g < 2; ++g) {
      float4 hv = make_float4(0.f, 0.f, 0.f, 0.f);
      if (n < N) hv = *reinterpret_cast<const float4*>(h + (size_t)n * ND + g*64 + tx*4);
      v[g*4+0] = hv.x + acc[er][g*4+0]; v[g*4+1] = hv.y + acc[er][g*4+1];
      v[g*4+2] = hv.z + acc[er][g*4+2]; v[g*4+3] = hv.w + acc[er][g*4+3];
    }
    #pragma unroll
    for (int q = 0; q < 8; ++q) { s += v[q]; s2 += v[q]*v[q]; }
    #pragma unroll
    for (int off = 1; off < 16; off <<= 1) {
      s  += __shfl_xor(s,  off, 16);
      s2 += __shfl_xor(s2, off, 16);
    }
    const float mu   = s * (1.f / 128.f);
    const float var  = s2 * (1.f / 128.f) - mu * mu;
    const float rstd = rsqrtf(var + 1e-5f);
    if (n < N) {
      #pragma unroll
      for (int g = 0; g < 2; ++g) {
        float4 gv = *reinterpret_cast<const float4*>(gamma + g*64 + tx*4);
        float4 bv = *reinterpret_cast<const float4*>(beta  + g*64 + tx*4);
        float4 o;
        o.x = (v[g*4+0]-mu)*rstd*gv.x + bv.x;
        o.y = (v[g*4+1]-mu)*rstd*gv.y + bv.y;
        o.z = (v[g*4+2]-mu)*rstd*gv.z + bv.z;
        o.w = (v[g*4+3]-mu)*rstd*gv.w + bv.w;
        *reinterpret_cast<float4*>(hout + (size_t)n * ND + g*64 + tx*4) = o;
      }
    }
  }
}

__global__ void egnn_xout_kernel(const float* __restrict__ x, const float* __restrict__ x_agg,
                                 float* __restrict__ xout, int total)
{
  int i = blockIdx.x * 256 + threadIdx.x;
  if (i < total) xout[i] = x[i] + x_agg[i];
}

extern "C" void kernel_launch(void* const* d_in, const int* in_sizes, int n_in,
                              void* d_out, int out_size, void* d_ws, size_t ws_size,
                              hipStream_t stream)
{
  const float* h     = (const float*)d_in[0];
  const float* x     = (const float*)d_in[1];
  const int*   eidx  = (const int*)  d_in[2];
  const float* eattr = (const float*)d_in[3];
  const float* mW1   = (const float*)d_in[4];
  const float* mb1   = (const float*)d_in[5];
  const float* mW2   = (const float*)d_in[6];
  const float* mb2   = (const float*)d_in[7];
  const float* nW1   = (const float*)d_in[8];
  const float* nb1   = (const float*)d_in[9];
  const float* nW2   = (const float*)d_in[10];
  const float* nb2   = (const float*)d_in[11];
  const float* cW1   = (const float*)d_in[12];
  const float* cb1   = (const float*)d_in[13];
  const float* cW2   = (const float*)d_in[14];
  const float* gamma = (const float*)d_in[15];
  const float* beta  = (const float*)d_in[16];

  const int N = in_sizes[0] / ND;
  const int E = in_sizes[2] / 2;

  float* m_i   = (float*)d_ws;                       // [N, HD]
  float* x_agg = m_i + (size_t)N * HD;               // [N, 3]
  float* t1    = x_agg + (size_t)N * 3;              // [N, HD]

  float* hout = (float*)d_out;                       // [N, ND]
  float* xout = hout + (size_t)N * ND;               // [N, 3]

  hipMemsetAsync(m_i,   0, (size_t)N * HD * sizeof(float), stream);
  hipMemsetAsync(x_agg, 0, (size_t)N * 3  * sizeof(float), stream);

  egnn_edge_kernel<<<(E + 63) / 64, 512, 0, stream>>>(
      h, x, eidx, eattr, mW1, mb1, mW2, mb2, cW1, cb1, cW2, m_i, x_agg, N, E);
  egnn_node1_kernel<<<(N + 63) / 64, 512, 0, stream>>>(h, m_i, nW1, nb1, t1, N);
  egnn_node2_kernel<<<(N + 63) / 64, 512, 0, stream>>>(t1, h, nW2, nb2, gamma, beta, hout, N);
  egnn_xout_kernel<<<(N * 3 + 255) / 256, 256, 0, stream>>>(x, x_agg, xout, N * 3);
}

// Round 3
// 1414.845 us; speedup vs baseline: 6.8827x; 6.8827x over previous
//
#include <hip/hip_runtime.h>

#define ND 128
#define ED 32
#define HD 256
#define ASTR 296   // edge A-tile LDS row stride (bf16 elems): 16B-aligned, 2-way-free banks
#define NSTR 392   // node A-tile LDS row stride (K=384 + pad)

typedef short bf16x8 __attribute__((ext_vector_type(8)));
typedef float f32x4 __attribute__((ext_vector_type(4)));

__device__ __forceinline__ float silu_f(float v) {
  return v / (1.0f + __expf(-v));
}

__device__ __forceinline__ unsigned short bf_hi(float f) {
  unsigned int u = __float_as_uint(f);
  return (unsigned short)((u + 0x7FFFu + ((u >> 16) & 1u)) >> 16);
}
__device__ __forceinline__ float bf_to_f(unsigned short s) {
  return __uint_as_float(((unsigned int)s) << 16);
}
__device__ __forceinline__ void split2(float f, unsigned short& hi, unsigned short& lo) {
  hi = bf_hi(f);
  lo = bf_hi(f - bf_to_f(hi));
}
__device__ __forceinline__ void store_split4(unsigned short* hp, unsigned short* lp, float4 v) {
  ushort4 h4, l4;
  split2(v.x, h4.x, l4.x); split2(v.y, h4.y, l4.y);
  split2(v.z, h4.z, l4.z); split2(v.w, h4.w, l4.w);
  *reinterpret_cast<ushort4*>(hp) = h4;
  *reinterpret_cast<ushort4*>(lp) = l4;
}

// ---------------------------------------------------------------------------
// Weight fragment prep: W[K x Ncols] fp32 -> hi/lo bf16 arrays in MFMA B-frag
// order [s][tile][lane][8]:  k = s*32 + (lane>>4)*8 + j,  n = tile*16 + (lane&15).
// skiprow>=0: k >= skiprow maps to W row k+1 (edge dist row handled separately).
// ---------------------------------------------------------------------------
__global__ void prep_frag(const float* __restrict__ W, unsigned short* __restrict__ Fh,
                          unsigned short* __restrict__ Fl, int Keff, int Ncols, int S,
                          int skiprow)
{
  int idx = blockIdx.x * 256 + threadIdx.x;
  int NT = Ncols >> 4;
  int total = S * NT * 64;
  if (idx >= total) return;
  int lane = idx & 63;
  int k0 = (idx / (NT * 64)) * 32 + ((lane >> 4) << 3);
  int n = ((idx >> 6) % NT) * 16 + (lane & 15);
  size_t base = (size_t)idx * 8;
  for (int j = 0; j < 8; ++j) {
    int k = k0 + j;
    float v = 0.f;
    if (k < Keff) {
      int wk = (skiprow >= 0 && k >= skiprow) ? (k + 1) : k;
      v = W[(size_t)wk * Ncols + n];
    }
    unsigned short hi, lo; split2(v, hi, lo);
    Fh[base + j] = hi; Fl[base + j] = lo;
  }
}

// ---------------------------------------------------------------------------
// Split-bf16 MFMA GEMM over a 64-row LDS A-tile.
// Wave covers NTW 16-col tiles starting at tile wave*NTW; 4 m-tiles of 16 rows.
// A-frag: row = mt*16 + (lane&15), k = s*32 + (lane>>4)*8 + j  (ds_read_b128).
// 3 MFMAs per product: hi*hi + hi*lo + lo*hi (err ~2^-17).
// ---------------------------------------------------------------------------
template<int STRIDE, int NT, int NTW>
__device__ __forceinline__ void mfma_gemm(const unsigned short* __restrict__ Ahi,
                                          const unsigned short* __restrict__ Alo,
                                          const unsigned short* __restrict__ Bh,
                                          const unsigned short* __restrict__ Bl,
                                          int S, int wave, int lane, f32x4 acc[4][NTW])
{
  const int tx = lane & 15, tz = lane >> 4;
  for (int s = 0; s < S; ++s) {
    bf16x8 bh[NTW], bl[NTW], ah[4], al[4];
    #pragma unroll
    for (int nt = 0; nt < NTW; ++nt) {
      size_t bidx = ((size_t)(s * NT + wave * NTW + nt) * 64 + lane) * 8;
      bh[nt] = *reinterpret_cast<const bf16x8*>(Bh + bidx);
      bl[nt] = *reinterpret_cast<const bf16x8*>(Bl + bidx);
    }
    const int koff = s * 32 + tz * 8;
    #pragma unroll
    for (int mt = 0; mt < 4; ++mt) {
      size_t aoff = (size_t)(mt * 16 + tx) * STRIDE + koff;
      ah[mt] = *reinterpret_cast<const bf16x8*>(Ahi + aoff);
      al[mt] = *reinterpret_cast<const bf16x8*>(Alo + aoff);
    }
    #pragma unroll
    for (int mt = 0; mt < 4; ++mt) {
      #pragma unroll
      for (int nt = 0; nt < NTW; ++nt) {
        acc[mt][nt] = __builtin_amdgcn_mfma_f32_16x16x32_bf16(ah[mt], bh[nt], acc[mt][nt], 0, 0, 0);
        acc[mt][nt] = __builtin_amdgcn_mfma_f32_16x16x32_bf16(ah[mt], bl[nt], acc[mt][nt], 0, 0, 0);
        acc[mt][nt] = __builtin_amdgcn_mfma_f32_16x16x32_bf16(al[mt], bh[nt], acc[mt][nt], 0, 0, 0);
      }
    }
  }
}

// ---------------------------------------------------------------------------
// Edge kernel: 64 edges/block, 512 threads (8 waves).
// edge_in LDS cols: [0..127]=h[row], [128..255]=h[col], [256..287]=edge_attr.
// dist_sq handled as exact fp32 rank-1 update with mW1 row 256.
// GEMM1 (S=9,K=288) -> m1 overlay -> GEMM2 (S=8) -> m_i atomics + m overlay
// -> GEMM3 (S=8) -> cW2 GEMV reduce -> x_agg atomics.
// LDS: 2*64*296*2B + misc = 77.3 KB -> 2 blocks/CU.
// ---------------------------------------------------------------------------
__global__ __launch_bounds__(512, 4)
void egnn_edge_mfma(const float* __restrict__ h, const float* __restrict__ x,
                    const int* __restrict__ eidx, const float* __restrict__ eattr,
                    const float* __restrict__ mW1, const float* __restrict__ mb1,
                    const float* __restrict__ mb2, const float* __restrict__ cb1,
                    const float* __restrict__ cW2,
                    const unsigned short* __restrict__ W1h, const unsigned short* __restrict__ W1l,
                    const unsigned short* __restrict__ W2h, const unsigned short* __restrict__ W2l,
                    const unsigned short* __restrict__ C1h, const unsigned short* __restrict__ C1l,
                    float* __restrict__ m_i, float* __restrict__ x_agg, int E)
{
  __shared__ unsigned short Ahi[64][ASTR];
  __shared__ unsigned short Alo[64][ASTR];
  __shared__ int   sRow[64];
  __shared__ float sDx0[64], sDx1[64], sDx2[64], sDist[64], sCoef[64];

  const int t  = threadIdx.x;
  const int e0 = blockIdx.x * 64;
  if (t < 64) sCoef[t] = 0.f;

  { // ---- stage + bf16-split: 8 threads per edge ----
    const int e = t >> 3, part = t & 7;
    const int ge = e0 + e;
    if (ge < E) {
      const int r = eidx[ge], c = eidx[E + ge];
      const float* hsrc = (part < 4) ? (h + (size_t)r * ND + (part & 3) * 32)
                                     : (h + (size_t)c * ND + (part & 3) * 32);
      const int cb = (part < 4 ? 0 : 128) + (part & 3) * 32;
      #pragma unroll
      for (int i = 0; i < 8; ++i) {
        float4 v = reinterpret_cast<const float4*>(hsrc)[i];
        store_split4(&Ahi[e][cb + i * 4], &Alo[e][cb + i * 4], v);
      }
      float4 av = reinterpret_cast<const float4*>(eattr + (size_t)ge * ED)[part];
      store_split4(&Ahi[e][256 + part * 4], &Alo[e][256 + part * 4], av);
      if (part == 0) {
        sRow[e] = r;
        float d0 = x[3*(size_t)r+0] - x[3*(size_t)c+0];
        float d1 = x[3*(size_t)r+1] - x[3*(size_t)c+1];
        float d2 = x[3*(size_t)r+2] - x[3*(size_t)c+2];
        sDx0[e] = d0; sDx1[e] = d1; sDx2[e] = d2;
        sDist[e] = d0*d0 + d1*d1 + d2*d2 + 1e-8f;
      }
    }
  }
  __syncthreads();

  const int lane = t & 63, wave = t >> 6;
  const int tx = lane & 15, tz = lane >> 4;
  const int c0 = wave * 32 + tx;
  const int c1 = c0 + 16;

  f32x4 acc[4][2];

  // ---- GEMM1: m1 = silu(edge_in @ mW1 + mb1); dist term exact fp32 ----
  {
    const float b0v = mb1[c0], b1v = mb1[c1];
    const float wA = mW1[(size_t)256 * HD + c0];
    const float wB = mW1[(size_t)256 * HD + c1];
    #pragma unroll
    for (int mt = 0; mt < 4; ++mt)
      #pragma unroll
      for (int r = 0; r < 4; ++r) {
        const float d = sDist[mt * 16 + tz * 4 + r];
        acc[mt][0][r] = b0v + d * wA;
        acc[mt][1][r] = b1v + d * wB;
      }
  }
  mfma_gemm<ASTR, 16, 2>(&Ahi[0][0], &Alo[0][0], W1h, W1l, 9, wave, lane, acc);
  __syncthreads();                       // all waves done READING edge_in
  #pragma unroll
  for (int mt = 0; mt < 4; ++mt)
    #pragma unroll
    for (int r = 0; r < 4; ++r) {
      const int row = mt * 16 + tz * 4 + r;
      unsigned short hi, lo;
      split2(silu_f(acc[mt][0][r]), hi, lo);
      Ahi[row][c0] = hi; Alo[row][c0] = lo;
      split2(silu_f(acc[mt][1][r]), hi, lo);
      Ahi[row][c1] = hi; Alo[row][c1] = lo;
    }
  __syncthreads();

  // ---- GEMM2: m = silu(m1 @ mW2 + mb2); scatter m_i ----
  {
    const float b0v = mb2[c0], b1v = mb2[c1];
    #pragma unroll
    for (int mt = 0; mt < 4; ++mt)
      #pragma unroll
      for (int r = 0; r < 4; ++r) { acc[mt][0][r] = b0v; acc[mt][1][r] = b1v; }
  }
  mfma_gemm<ASTR, 16, 2>(&Ahi[0][0], &Alo[0][0], W2h, W2l, 8, wave, lane, acc);
  #pragma unroll
  for (int mt = 0; mt < 4; ++mt)
    #pragma unroll
    for (int r = 0; r < 4; ++r) {
      acc[mt][0][r] = silu_f(acc[mt][0][r]);
      acc[mt][1][r] = silu_f(acc[mt][1][r]);
      const int row = mt * 16 + tz * 4 + r;
      if (e0 + row < E) {
        const size_t rn = (size_t)sRow[row] * HD;
        unsafeAtomicAdd(&m_i[rn + c0], acc[mt][0][r]);
        unsafeAtomicAdd(&m_i[rn + c1], acc[mt][1][r]);
      }
    }
  __syncthreads();                       // all waves done READING m1
  #pragma unroll
  for (int mt = 0; mt < 4; ++mt)
    #pragma unroll
    for (int r = 0; r < 4; ++r) {
      const int row = mt * 16 + tz * 4 + r;
      unsigned short hi, lo;
      split2(acc[mt][0][r], hi, lo);
      Ahi[row][c0] = hi; Alo[row][c0] = lo;
      split2(acc[mt][1][r], hi, lo);
      Ahi[row][c1] = hi; Alo[row][c1] = lo;
    }
  __syncthreads();

  // ---- GEMM3: coef = silu(m @ cW1 + cb1) @ cW2 ----
  {
    const float b0v = cb1[c0], b1v = cb1[c1];
    #pragma unroll
    for (int mt = 0; mt < 4; ++mt)
      #pragma unroll
      for (int r = 0; r < 4; ++r) { acc[mt][0][r] = b0v; acc[mt][1][r] = b1v; }
  }
  mfma_gemm<ASTR, 16, 2>(&Ahi[0][0], &Alo[0][0], C1h, C1l, 8, wave, lane, acc);
  {
    const float w20 = cW2[c0], w21 = cW2[c1];
    #pragma unroll
    for (int mt = 0; mt < 4; ++mt)
      #pragma unroll
      for (int r = 0; r < 4; ++r) {
        float v = silu_f(acc[mt][0][r]) * w20 + silu_f(acc[mt][1][r]) * w21;
        v += __shfl_xor(v, 1); v += __shfl_xor(v, 2);
        v += __shfl_xor(v, 4); v += __shfl_xor(v, 8);
        if (tx == 0) atomicAdd(&sCoef[mt * 16 + tz * 4 + r], v);
      }
  }
  __syncthreads();
  if (t < 64 && e0 + t < E) {
    const float cf = sCoef[t];
    const size_t rn = 3 * (size_t)sRow[t];
    unsafeAtomicAdd(&x_agg[rn + 0], sDx0[t] * cf);
    unsafeAtomicAdd(&x_agg[rn + 1], sDx1[t] * cf);
    unsafeAtomicAdd(&x_agg[rn + 2], sDx2[t] * cf);
  }
}

// ---------------------------------------------------------------------------
// Fused node kernel: t1 = silu([h,m_i]@nW1+nb1) (K=384) kept in LDS ->
// h_res = h + t1@nW2 + nb2 (N=128) -> LayerNorm -> h_out.  64 nodes/block.
// ---------------------------------------------------------------------------
__global__ __launch_bounds__(512, 2)
void egnn_node_mfma(const float* __restrict__ h, const float* __restrict__ m_i,
                    const unsigned short* __restrict__ N1h, const unsigned short* __restrict__ N1l,
                    const unsigned short* __restrict__ N2h, const unsigned short* __restrict__ N2l,
                    const float* __restrict__ nb1, const float* __restrict__ nb2,
                    const float* __restrict__ gamma, const float* __restrict__ beta,
                    float* __restrict__ hout, int N)
{
  __shared__ unsigned short Ahi[64][NSTR];
  __shared__ unsigned short Alo[64][NSTR];
  __shared__ float sSum[64], sSum2[64];

  const int t  = threadIdx.x;
  const int n0 = blockIdx.x * 64;
  if (t < 64) { sSum[t] = 0.f; sSum2[t] = 0.f; }

  { // ---- stage [h | m_i] ----
    const int e = t >> 3, part = t & 7;
    const int n = n0 + e;
    if (n < N) {
      #pragma unroll
      for (int i = 0; i < 4; ++i) {
        float4 v = reinterpret_cast<const float4*>(h + (size_t)n * ND + part * 16)[i];
        store_split4(&Ahi[e][part * 16 + i * 4], &Alo[e][part * 16 + i * 4], v);
      }
      #pragma unroll
      for (int i = 0; i < 8; ++i) {
        float4 v = reinterpret_cast<const float4*>(m_i + (size_t)n * HD + part * 32)[i];
        store_split4(&Ahi[e][128 + part * 32 + i * 4], &Alo[e][128 + part * 32 + i * 4], v);
      }
    }
  }
  __syncthreads();

  const int lane = t & 63, wave = t >> 6;
  const int tx = lane & 15, tz = lane >> 4;

  { // ---- GEMM1: t1 = silu([h,m_i] @ nW1 + nb1), overlay into LDS ----
    const int c0 = wave * 32 + tx, c1 = c0 + 16;
    f32x4 acc[4][2];
    const float b0v = nb1[c0], b1v = nb1[c1];
    #pragma unroll
    for (int mt = 0; mt < 4; ++mt)
      #pragma unroll
      for (int r = 0; r < 4; ++r) { acc[mt][0][r] = b0v; acc[mt][1][r] = b1v; }
    mfma_gemm<NSTR, 16, 2>(&Ahi[0][0], &Alo[0][0], N1h, N1l, 12, wave, lane, acc);
    __syncthreads();
    #pragma unroll
    for (int mt = 0; mt < 4; ++mt)
      #pragma unroll
      for (int r = 0; r < 4; ++r) {
        const int row = mt * 16 + tz * 4 + r;
        unsigned short hi, lo;
        split2(silu_f(acc[mt][0][r]), hi, lo);
        Ahi[row][c0] = hi; Alo[row][c0] = lo;
        split2(silu_f(acc[mt][1][r]), hi, lo);
        Ahi[row][c1] = hi; Alo[row][c1] = lo;
      }
    __syncthreads();
  }

  // ---- GEMM2: h_res = h + t1 @ nW2 + nb2  (N=128: 1 tile/wave) ----
  const int col = wave * 16 + tx;
  f32x4 a2[4][1];
  {
    const float bv = nb2[col];
    #pragma unroll
    for (int mt = 0; mt < 4; ++mt)
      #pragma unroll
      for (int r = 0; r < 4; ++r) a2[mt][0][r] = bv;
  }
  mfma_gemm<NSTR, 8, 1>(&Ahi[0][0], &Alo[0][0], N2h, N2l, 8, wave, lane, a2);

  // ---- epilogue: residual + LayerNorm ----
  const float g  = gamma[col];
  const float bt = beta[col];
  float vv[4][4];
  #pragma unroll
  for (int mt = 0; mt < 4; ++mt)
    #pragma unroll
    for (int r = 0; r < 4; ++r) {
      const int row = mt * 16 + tz * 4 + r;
      const int n = n0 + row;
      const float hv = (n < N) ? h[(size_t)n * ND + col] : 0.f;
      const float v = a2[mt][0][r] + hv;
      vv[mt][r] = v;
      float s1 = v, s2 = v * v;
      s1 += __shfl_xor(s1, 1); s1 += __shfl_xor(s1, 2);
      s1 += __shfl_xor(s1, 4); s1 += __shfl_xor(s1, 8);
      s2 += __shfl_xor(s2, 1); s2 += __shfl_xor(s2, 2);
      s2 += __shfl_xor(s2, 4); s2 += __shfl_xor(s2, 8);
      if (tx == 0) {
        atomicAdd(&sSum[row],  s1);
        atomicAdd(&sSum2[row], s2);
      }
    }
  __syncthreads();
  #pragma unroll
  for (int mt = 0; mt < 4; ++mt)
    #pragma unroll
    for (int r = 0; r < 4; ++r) {
      const int row = mt * 16 + tz * 4 + r;
      const int n = n0 + row;
      if (n < N) {
        const float mu   = sSum[row] * (1.f / 128.f);
        const float var  = sSum2[row] * (1.f / 128.f) - mu * mu;
        const float rstd = rsqrtf(var + 1e-5f);
        hout[(size_t)n * ND + col] = (vv[mt][r] - mu) * rstd * g + bt;
      }
    }
}

__global__ void egnn_xout_kernel(const float* __restrict__ x, const float* __restrict__ x_agg,
                                 float* __restrict__ xout, int total)
{
  int i = blockIdx.x * 256 + threadIdx.x;
  if (i < total) xout[i] = x[i] + x_agg[i];
}

extern "C" void kernel_launch(void* const* d_in, const int* in_sizes, int n_in,
                              void* d_out, int out_size, void* d_ws, size_t ws_size,
                              hipStream_t stream)
{
  const float* h     = (const float*)d_in[0];
  const float* x     = (const float*)d_in[1];
  const int*   eidx  = (const int*)  d_in[2];
  const float* eattr = (const float*)d_in[3];
  const float* mW1   = (const float*)d_in[4];
  const float* mb1   = (const float*)d_in[5];
  const float* mW2   = (const float*)d_in[6];
  const float* mb2   = (const float*)d_in[7];
  const float* nW1   = (const float*)d_in[8];
  const float* nb1   = (const float*)d_in[9];
  const float* nW2   = (const float*)d_in[10];
  const float* nb2   = (const float*)d_in[11];
  const float* cW1   = (const float*)d_in[12];
  const float* cb1   = (const float*)d_in[13];
  const float* cW2   = (const float*)d_in[14];
  const float* gamma = (const float*)d_in[15];
  const float* beta  = (const float*)d_in[16];

  const int N = in_sizes[0] / ND;
  const int E = in_sizes[2] / 2;

  float* m_i   = (float*)d_ws;                       // [N, HD] fp32
  float* x_agg = m_i + (size_t)N * HD;               // [N, 3]  fp32
  unsigned short* fr = (unsigned short*)(x_agg + (size_t)N * 3);

  const int SZ_W1 = 9  * 16 * 64 * 8;   // mW1 frags (K=288 w/ dist-row skip)
  const int SZ_W2 = 8  * 16 * 64 * 8;   // mW2 / cW1 frags (K=256, N=256)
  const int SZ_N1 = 12 * 16 * 64 * 8;   // nW1 frags (K=384, N=256)
  const int SZ_N2 = 8  * 8  * 64 * 8;   // nW2 frags (K=256, N=128)
  unsigned short* W1h = fr; fr += SZ_W1;
  unsigned short* W1l = fr; fr += SZ_W1;
  unsigned short* W2h = fr; fr += SZ_W2;
  unsigned short* W2l = fr; fr += SZ_W2;
  unsigned short* C1h = fr; fr += SZ_W2;
  unsigned short* C1l = fr; fr += SZ_W2;
  unsigned short* N1h = fr; fr += SZ_N1;
  unsigned short* N1l = fr; fr += SZ_N1;
  unsigned short* N2h = fr; fr += SZ_N2;
  unsigned short* N2l = fr; fr += SZ_N2;

  float* hout = (float*)d_out;                       // [N, ND]
  float* xout = hout + (size_t)N * ND;               // [N, 3]

  hipMemsetAsync(m_i,   0, (size_t)N * HD * sizeof(float), stream);
  hipMemsetAsync(x_agg, 0, (size_t)N * 3  * sizeof(float), stream);

  prep_frag<<<(9*16*64  + 255)/256, 256, 0, stream>>>(mW1, W1h, W1l, 288, 256,  9, 256);
  prep_frag<<<(8*16*64  + 255)/256, 256, 0, stream>>>(mW2, W2h, W2l, 256, 256,  8,  -1);
  prep_frag<<<(8*16*64  + 255)/256, 256, 0, stream>>>(cW1, C1h, C1l, 256, 256,  8,  -1);
  prep_frag<<<(12*16*64 + 255)/256, 256, 0, stream>>>(nW1, N1h, N1l, 384, 256, 12,  -1);
  prep_frag<<<(8*8*64   + 255)/256, 256, 0, stream>>>(nW2, N2h, N2l, 256, 128,  8,  -1);

  egnn_edge_mfma<<<(E + 63) / 64, 512, 0, stream>>>(
      h, x, eidx, eattr, mW1, mb1, mb2, cb1, cW2,
      W1h, W1l, W2h, W2l, C1h, C1l, m_i, x_agg, E);
  egnn_node_mfma<<<(N + 63) / 64, 512, 0, stream>>>(
      h, m_i, N1h, N1l, N2h, N2l, nb1, nb2, gamma, beta, hout, N);
  egnn_xout_kernel<<<(N * 3 + 255) / 256, 256, 0, stream>>>(x, x_agg, xout, N * 3);
}